// Round 20
// baseline (393.822 us; speedup 1.0000x reference)
//
#include <hip/hip_runtime.h>
#include <hip/hip_cooperative_groups.h>
#include <math.h>

namespace cg = cooperative_groups;

#define B_ 32
#define H_ 112
#define W_ 112
#define C_ 128
#define R_ 2048
#define HW_ (H_ * W_)      // 12544
#define C4_ (C_ / 4)       // 32 float4 per pixel
#define PB_ 32             // pool chunks per batch
#define RB_ 8              // r-blocks per batch in fc (256 r each)
#define NB_ (B_ * PB_)     // 1024 blocks, 4/CU on 256 CUs -> co-resident

typedef float f32x4_t __attribute__((ext_vector_type(4)));

// ---------------------------------------------------------------------------
// Fused cooperative kernel: pool -> grid.sync -> fc1+fc2 -> grid.sync -> scale
// Round-18 profile: 322 us, 1.27 TB/s (16% peak), VGPR=32 -> load-latency
// bound with ~1 load in flight. This round: 8-deep load batching in both
// streaming phases (49 float4/thread = 6x8 + 1) to raise MLP.
// ---------------------------------------------------------------------------
__global__ __launch_bounds__(256, 4) void fused_kernel(
    const float4* __restrict__ x, const float* __restrict__ w1,
    const float* __restrict__ b1, const float4* __restrict__ w2,
    const float* __restrict__ b2, float4* __restrict__ part,
    float4* __restrict__ gpart, float4* __restrict__ out)
{
    cg::grid_group grid = cg::this_grid();
    const int blk = blockIdx.x;
    const int t   = threadIdx.x;

    __shared__ float4 red[256];
    __shared__ float  sl[C_];
    __shared__ float  hl[256];

    // ---- phase 1: pool partials (8 loads in flight per wave) ----
    {
        const int b     = blk >> 5;          // 0..31
        const int pb    = blk & 31;          // 0..31
        const int lane4 = t & 31;
        const int prow  = t >> 5;
        const int ppb   = HW_ / PB_;         // 392 pixels -> 49 per thread
        const int p0    = pb * ppb;
        const float4* px = x + (size_t)b * HW_ * C4_
                             + (size_t)(p0 + prow) * C4_ + lane4;
        const size_t step = (size_t)8 * C4_; // 8-pixel stride per k

        float4 a0 = make_float4(0.f,0.f,0.f,0.f), a1 = a0, a2 = a0, a3 = a0;
        for (int j = 0; j < 6; ++j) {        // 6 batches of 8 = 48
            const size_t o = (size_t)(8 * j) * step;
            float4 v0 = px[o + 0 * step];
            float4 v1 = px[o + 1 * step];
            float4 v2 = px[o + 2 * step];
            float4 v3 = px[o + 3 * step];
            float4 v4 = px[o + 4 * step];
            float4 v5 = px[o + 5 * step];
            float4 v6 = px[o + 6 * step];
            float4 v7 = px[o + 7 * step];
            a0.x += v0.x + v4.x; a0.y += v0.y + v4.y; a0.z += v0.z + v4.z; a0.w += v0.w + v4.w;
            a1.x += v1.x + v5.x; a1.y += v1.y + v5.y; a1.z += v1.z + v5.z; a1.w += v1.w + v5.w;
            a2.x += v2.x + v6.x; a2.y += v2.y + v6.y; a2.z += v2.z + v6.z; a2.w += v2.w + v6.w;
            a3.x += v3.x + v7.x; a3.y += v3.y + v7.y; a3.z += v3.z + v7.z; a3.w += v3.w + v7.w;
        }
        float4 vt = px[(size_t)48 * step];   // tail (49th)
        float4 acc;
        acc.x = (a0.x + a1.x) + (a2.x + a3.x) + vt.x;
        acc.y = (a0.y + a1.y) + (a2.y + a3.y) + vt.y;
        acc.z = (a0.z + a1.z) + (a2.z + a3.z) + vt.z;
        acc.w = (a0.w + a1.w) + (a2.w + a3.w) + vt.w;

        red[t] = acc;
        __syncthreads();
        if (t < 32) {
            float4 a = red[t];
#pragma unroll
            for (int k = 1; k < 8; ++k) {
                float4 v = red[t + 32 * k];
                a.x += v.x; a.y += v.y; a.z += v.z; a.w += v.w;
            }
            part[((size_t)b * PB_ + pb) * C4_ + t] = a;
        }
    }
    grid.sync();

    // ---- phase 2: fc1+fc2 partial (unchanged), blocks 0..255 ----
    if (blk < B_ * RB_) {
        const int b  = blk >> 3;
        const int rb = blk & 7;
        const int r  = rb * 256 + t;

        if (t < 32) {
            float4 a = make_float4(0.f, 0.f, 0.f, 0.f);
#pragma unroll 8
            for (int k = 0; k < PB_; ++k) {
                float4 v = part[((size_t)b * PB_ + k) * C4_ + t];
                a.x += v.x; a.y += v.y; a.z += v.z; a.w += v.w;
            }
            const float inv = 1.0f / (float)HW_;
            sl[t * 4 + 0] = a.x * inv;
            sl[t * 4 + 1] = a.y * inv;
            sl[t * 4 + 2] = a.z * inv;
            sl[t * 4 + 3] = a.w * inv;
        }
        __syncthreads();

        float acc = b1[r];
#pragma unroll 8
        for (int c = 0; c < C_; ++c)
            acc += sl[c] * w1[(size_t)c * R_ + r];

        // tanh-approx GELU
        const float xv = acc;
        const float tn = tanhf(0.7978845608028654f * (xv + 0.044715f * xv * xv * xv));
        hl[t] = 0.5f * xv * (1.0f + tn);
        __syncthreads();

        const int c4 = t & 31;
        const int ks = t >> 5;
        float4 a2 = make_float4(0.f, 0.f, 0.f, 0.f);
        const int rr0 = ks * 32;
#pragma unroll 8
        for (int rr = rr0; rr < rr0 + 32; ++rr) {
            const float hv = hl[rr];
            float4 w = w2[(size_t)(rb * 256 + rr) * C4_ + c4];
            a2.x += hv * w.x; a2.y += hv * w.y; a2.z += hv * w.z; a2.w += hv * w.w;
        }
        red[t] = a2;
        __syncthreads();
        if (t < 32) {
            float4 a = red[t];
#pragma unroll
            for (int k = 1; k < 8; ++k) {
                float4 v = red[t + 32 * k];
                a.x += v.x; a.y += v.y; a.z += v.z; a.w += v.w;
            }
            gpart[((size_t)b * RB_ + rb) * C4_ + t] = a;
        }
    }
    grid.sync();

    // ---- phase 3: scale with 8-deep load batching; NT stores unchanged ----
    {
        const int b  = blk >> 5;
        const int pb = blk & 31;
        const int c4 = t & 31;

        const float4* gp = gpart + (size_t)b * RB_ * C4_;
        float4 a = gp[c4];
#pragma unroll
        for (int k = 1; k < RB_; ++k) {
            float4 v = gp[(size_t)k * C4_ + c4];
            a.x += v.x; a.y += v.y; a.z += v.z; a.w += v.w;
        }
        a.x += b2[c4 * 4 + 0]; a.y += b2[c4 * 4 + 1];
        a.z += b2[c4 * 4 + 2]; a.w += b2[c4 * 4 + 3];
        float4 gv;
        gv.x = 1.0f / (1.0f + expf(-a.x));
        gv.y = 1.0f / (1.0f + expf(-a.y));
        gv.z = 1.0f / (1.0f + expf(-a.z));
        gv.w = 1.0f / (1.0f + expf(-a.w));

        const int ppb = HW_ / PB_;                       // 392 pixels
        const size_t base = (size_t)b * HW_ * C4_ + (size_t)pb * ppb * C4_;
        const float4* xp = x + base;
        float4* op = out + base;
        // 49 float4 per thread at stride 256: 6 batches of 8 + 1 tail
        int i = t;
        for (int j = 0; j < 6; ++j) {
            float4 v0 = xp[i + 0 * 256];
            float4 v1 = xp[i + 1 * 256];
            float4 v2 = xp[i + 2 * 256];
            float4 v3 = xp[i + 3 * 256];
            float4 v4 = xp[i + 4 * 256];
            float4 v5 = xp[i + 5 * 256];
            float4 v6 = xp[i + 6 * 256];
            float4 v7 = xp[i + 7 * 256];
            f32x4_t o0, o1, o2, o3, o4, o5, o6, o7;
            o0.x = v0.x * gv.x; o0.y = v0.y * gv.y; o0.z = v0.z * gv.z; o0.w = v0.w * gv.w;
            o1.x = v1.x * gv.x; o1.y = v1.y * gv.y; o1.z = v1.z * gv.z; o1.w = v1.w * gv.w;
            o2.x = v2.x * gv.x; o2.y = v2.y * gv.y; o2.z = v2.z * gv.z; o2.w = v2.w * gv.w;
            o3.x = v3.x * gv.x; o3.y = v3.y * gv.y; o3.z = v3.z * gv.z; o3.w = v3.w * gv.w;
            o4.x = v4.x * gv.x; o4.y = v4.y * gv.y; o4.z = v4.z * gv.z; o4.w = v4.w * gv.w;
            o5.x = v5.x * gv.x; o5.y = v5.y * gv.y; o5.z = v5.z * gv.z; o5.w = v5.w * gv.w;
            o6.x = v6.x * gv.x; o6.y = v6.y * gv.y; o6.z = v6.z * gv.z; o6.w = v6.w * gv.w;
            o7.x = v7.x * gv.x; o7.y = v7.y * gv.y; o7.z = v7.z * gv.z; o7.w = v7.w * gv.w;
            __builtin_nontemporal_store(o0, (f32x4_t*)&op[i + 0 * 256]);
            __builtin_nontemporal_store(o1, (f32x4_t*)&op[i + 1 * 256]);
            __builtin_nontemporal_store(o2, (f32x4_t*)&op[i + 2 * 256]);
            __builtin_nontemporal_store(o3, (f32x4_t*)&op[i + 3 * 256]);
            __builtin_nontemporal_store(o4, (f32x4_t*)&op[i + 4 * 256]);
            __builtin_nontemporal_store(o5, (f32x4_t*)&op[i + 5 * 256]);
            __builtin_nontemporal_store(o6, (f32x4_t*)&op[i + 6 * 256]);
            __builtin_nontemporal_store(o7, (f32x4_t*)&op[i + 7 * 256]);
            i += 8 * 256;
        }
        // tail (49th element)
        {
            float4 v = xp[i];
            f32x4_t o;
            o.x = v.x * gv.x; o.y = v.y * gv.y; o.z = v.z * gv.z; o.w = v.w * gv.w;
            __builtin_nontemporal_store(o, (f32x4_t*)&op[i]);
        }
    }
}

// ---------------------------------------------------------------------------
// Proven 3-kernel pipeline (393.4 us, verified). Used whenever the stream is
// capturing (graph-safe path) or the coop launch is rejected.
// ---------------------------------------------------------------------------
__global__ __launch_bounds__(256) void pool_kernel(const float4* __restrict__ x,
                                                   float4* __restrict__ part) {
    const int b     = blockIdx.x;
    const int pb    = blockIdx.y;
    const int t     = threadIdx.x;
    const int lane4 = t & 31;
    const int prow  = t >> 5;

    const int pixels_per_block = HW_ / PB_;
    const int p0 = pb * pixels_per_block;
    const float4* xb = x + (size_t)b * HW_ * C4_;

    float4 acc = make_float4(0.f, 0.f, 0.f, 0.f);
    for (int p = p0 + prow; p < p0 + pixels_per_block; p += 8) {
        float4 v = xb[(size_t)p * C4_ + lane4];
        acc.x += v.x; acc.y += v.y; acc.z += v.z; acc.w += v.w;
    }

    __shared__ float4 red[256];
    red[t] = acc;
    __syncthreads();
    if (t < 32) {
        float4 a = red[t];
#pragma unroll
        for (int k = 1; k < 8; ++k) {
            float4 v = red[t + 32 * k];
            a.x += v.x; a.y += v.y; a.z += v.z; a.w += v.w;
        }
        part[((size_t)b * PB_ + pb) * C4_ + t] = a;
    }
}

__global__ __launch_bounds__(256) void fc_kernel(const float4* __restrict__ part,
                                                 const float* __restrict__ w1,
                                                 const float* __restrict__ b1,
                                                 const float4* __restrict__ w2,
                                                 float4* __restrict__ gpart) {
    const int b  = blockIdx.x >> 3;
    const int rb = blockIdx.x & 7;
    const int t  = threadIdx.x;
    const int r  = rb * 256 + t;

    __shared__ float  sl[C_];
    __shared__ float  hl[256];
    __shared__ float4 red[256];

    if (t < 32) {
        float4 a = make_float4(0.f, 0.f, 0.f, 0.f);
#pragma unroll 8
        for (int k = 0; k < PB_; ++k) {
            float4 v = part[((size_t)b * PB_ + k) * C4_ + t];
            a.x += v.x; a.y += v.y; a.z += v.z; a.w += v.w;
        }
        const float inv = 1.0f / (float)HW_;
        sl[t * 4 + 0] = a.x * inv;
        sl[t * 4 + 1] = a.y * inv;
        sl[t * 4 + 2] = a.z * inv;
        sl[t * 4 + 3] = a.w * inv;
    }
    __syncthreads();

    float acc = b1[r];
#pragma unroll 8
    for (int c = 0; c < C_; ++c)
        acc += sl[c] * w1[(size_t)c * R_ + r];

    const float xv = acc;
    const float tn = tanhf(0.7978845608028654f * (xv + 0.044715f * xv * xv * xv));
    hl[t] = 0.5f * xv * (1.0f + tn);
    __syncthreads();

    const int c4 = t & 31;
    const int ks = t >> 5;
    float4 a2 = make_float4(0.f, 0.f, 0.f, 0.f);
    const int rr0 = ks * 32;
#pragma unroll 8
    for (int rr = rr0; rr < rr0 + 32; ++rr) {
        const float hv = hl[rr];
        float4 w = w2[(size_t)(rb * 256 + rr) * C4_ + c4];
        a2.x += hv * w.x; a2.y += hv * w.y; a2.z += hv * w.z; a2.w += hv * w.w;
    }
    red[t] = a2;
    __syncthreads();
    if (t < 32) {
        float4 a = red[t];
#pragma unroll
        for (int k = 1; k < 8; ++k) {
            float4 v = red[t + 32 * k];
            a.x += v.x; a.y += v.y; a.z += v.z; a.w += v.w;
        }
        gpart[((size_t)b * RB_ + rb) * C4_ + t] = a;
    }
}

__global__ __launch_bounds__(256) void scale_kernel(const float4* __restrict__ x,
                                                    const float4* __restrict__ gpart,
                                                    const float* __restrict__ b2,
                                                    float4* __restrict__ out) {
    const int b  = blockIdx.x;
    const int t  = threadIdx.x;
    const int c4 = t & 31;

    const float4* gp = gpart + (size_t)b * RB_ * C4_;
    float4 a = gp[c4];
#pragma unroll
    for (int k = 1; k < RB_; ++k) {
        float4 v = gp[(size_t)k * C4_ + c4];
        a.x += v.x; a.y += v.y; a.z += v.z; a.w += v.w;
    }
    a.x += b2[c4 * 4 + 0]; a.y += b2[c4 * 4 + 1];
    a.z += b2[c4 * 4 + 2]; a.w += b2[c4 * 4 + 3];
    float4 gv;
    gv.x = 1.0f / (1.0f + expf(-a.x));
    gv.y = 1.0f / (1.0f + expf(-a.y));
    gv.z = 1.0f / (1.0f + expf(-a.z));
    gv.w = 1.0f / (1.0f + expf(-a.w));

    const size_t base = (size_t)b * HW_ * C4_;
    const int total = HW_ * C4_;
    const int stride = gridDim.y * 256;

    for (int i = blockIdx.y * 256 + t; i < total; i += stride) {
        float4 v = x[base + i];
        f32x4_t o;
        o.x = v.x * gv.x; o.y = v.y * gv.y; o.z = v.z * gv.z; o.w = v.w * gv.w;
        __builtin_nontemporal_store(o, (f32x4_t*)&out[base + i]);
    }
}

extern "C" void kernel_launch(void* const* d_in, const int* in_sizes, int n_in,
                              void* d_out, int out_size, void* d_ws, size_t ws_size,
                              hipStream_t stream) {
    const float4* x  = (const float4*)d_in[0];
    const float*  w1 = (const float*)d_in[1];
    const float*  b1 = (const float*)d_in[2];
    const float4* w2 = (const float4*)d_in[3];
    const float*  b2 = (const float*)d_in[4];
    float4* out = (float4*)d_out;

    // workspace: part[B*PB_*C] (512 KB) | gpart[B*RB_*C] (128 KB)
    float4* part  = (float4*)d_ws;
    float4* gpart = (float4*)((float*)d_ws + B_ * PB_ * C_);

    // Coop launch inside a capturing stream can abort the process; query
    // capture state first and only use the coop path when not capturing.
    hipStreamCaptureStatus cap = hipStreamCaptureStatusNone;
    unsigned long long cap_id = 0;
    (void)hipStreamGetCaptureInfo(stream, &cap, &cap_id);

    if (cap == hipStreamCaptureStatusNone) {
        void* args[] = {(void*)&x, (void*)&w1, (void*)&b1, (void*)&w2,
                        (void*)&b2, (void*)&part, (void*)&gpart, (void*)&out};
        hipError_t err = hipLaunchCooperativeKernel((void*)fused_kernel,
                                                    dim3(NB_), dim3(256),
                                                    args, 0, stream);
        if (err == hipSuccess) return;
        (void)hipGetLastError();  // clear sticky error before fallback
    }

    // Graph-safe proven pipeline (393.4 us verified).
    pool_kernel<<<dim3(B_, PB_), 256, 0, stream>>>(x, part);
    fc_kernel<<<B_ * RB_, 256, 0, stream>>>(part, w1, b1, w2, gpart);
    scale_kernel<<<dim3(B_, 64), 256, 0, stream>>>(x, gpart, (const float*)b2, out);
}